// Round 20
// baseline (296.162 us; speedup 1.0000x reference)
//
#include <hip/hip_runtime.h>
#include <cmath>

#define NUM_CLS 58

typedef _Float16 v8h __attribute__((ext_vector_type(8)));
typedef float v4f __attribute__((ext_vector_type(4)));
union HU { v8h h; uint4 u; };

// ---------------- prep v3: 256-thread blocks, coalesced staging ----------------
__global__ __launch_bounds__(256) void prep_all(
    const float* __restrict__ w0, const float* __restrict__ w1,
    const float* __restrict__ w2, const float* __restrict__ w3,
    const float* __restrict__ w4,
    unsigned long long* __restrict__ wb1, unsigned long long* __restrict__ wb2,
    unsigned long long* __restrict__ wb3, unsigned long long* __restrict__ wb4,
    _Float16* __restrict__ bsig, _Float16* __restrict__ babs) {
    int id = blockIdx.x, tid = threadIdx.x;
    int lane = tid & 63, wv = tid >> 6;
    if (id < 384) {
        int layer = id >> 7, oc = id & 127;
        const float* w = layer == 0 ? w1 : (layer == 1 ? w2 : w3);
        unsigned long long* o = layer == 0 ? wb1 : (layer == 1 ? wb2 : wb3);
        __shared__ float s[1152];
        const float* base = w + (size_t)oc * 1152;
        for (int i = tid; i < 1152; i += 256) s[i] = base[i];   // coalesced
        __syncthreads();
        for (int k = wv; k < 9; k += 4) {    // stride-9 LDS reads: 2-way banks, free
            unsigned long long b0 = __ballot(s[lane * 9 + k] >= 0.f);
            unsigned long long b1 = __ballot(s[(lane + 64) * 9 + k] >= 0.f);
            if (lane == 0) { o[(oc * 9 + k) * 2] = b0; o[(oc * 9 + k) * 2 + 1] = b1; }
        }
    } else if (id < 416) {
        int oc = (id - 384) * 4 + wv;        // 128 oc over 32 blocks x 4 waves
        unsigned long long b0 = __ballot(w4[oc * 128 + lane] >= 0.f);
        unsigned long long b1 = __ballot(w4[oc * 128 + lane + 64] >= 0.f);
        if (lane == 0) { wb4[oc * 2] = b0; wb4[oc * 2 + 1] = b1; }
    } else {
        int nt = (id - 416) * 4 + wv;        // 8 nt over 2 blocks x 4 waves
        int n = nt * 16 + (lane & 15);
        int k0 = (lane >> 4) * 8;
#pragma unroll
        for (int j = 0; j < 8; j++) {
            int k = k0 + j;
            float v = (k < 27) ? w0[n * 27 + k] : 0.f;
            bsig[(nt * 64 + lane) * 8 + j] = (_Float16)v;
            babs[(nt * 64 + lane) * 8 + j] = (_Float16)fabsf(v);
        }
    }
}

// ---- one block per batch element, 512 threads (8 waves) ----
// Occupancy unlock: grid 1024 = 4 blocks/CU; 8-wave blocks -> 32 waves/CU
// (vs 16 with 4-wave blocks; measured occupancy was ~33%). launch_bounds(512,8)
// makes the allocator's perennial 64-VGPR choice exactly right (8 waves x 64 =
// 512 VGPR file). Per-thread code = round 17 (spill-free; WRITE_SIZE is canary).
__global__ __launch_bounds__(512, 8) void fused_net(
    const float* __restrict__ x, const float* __restrict__ w0,
    const _Float16* __restrict__ bsigG, const _Float16* __restrict__ babsG,
    const unsigned long long* __restrict__ wb1, const unsigned long long* __restrict__ wb2,
    const unsigned long long* __restrict__ wb3, const unsigned long long* __restrict__ wb4,
    const float* __restrict__ w5, float* __restrict__ out) {
    __shared__ _Float16 xh[3172];              // image f16; row stride 33, chan stride 1057
    __shared__ uint4 bfrag[512];               // B sign-fragments (8 KB)
    __shared__ uint4 bfraga[512];              // |B| fragments (8 KB)
    __shared__ alignas(16) unsigned long long bits1[450];  // [15*15][2]
    __shared__ alignas(16) unsigned long long bits2[72];
    __shared__ unsigned long long bits3[18];
    __shared__ unsigned long long bits4[2];
    __shared__ float r_s[128];
    __shared__ float l_s[NUM_CLS];
    __shared__ float e_s[NUM_CLS];
    __shared__ unsigned int qcnt;
    __shared__ unsigned int queue[256];

    int b = blockIdx.x;
    int tid = threadIdx.x;
    int lane = tid & 63, wave = tid >> 6;      // wave 0..7
    const float* xb = x + (size_t)b * 3072;

    // ================= phase 0: conv0 via f16 MFMA (pool-ordered im2col) =================
    {
        for (int i = tid; i < 3072; i += 512) {
            int c = i >> 10, rem = i & 1023;
            xh[c * 1057 + (rem >> 5) * 33 + (rem & 31)] = (_Float16)xb[i];  // cvt at staging
        }
        const uint4* bs4 = (const uint4*)bsigG;
        const uint4* ba4 = (const uint4*)babsG;
        for (int i = tid; i < 512; i += 512) { bfrag[i] = bs4[i]; bfraga[i] = ba4[i]; }
        if (tid == 0) qcnt = 0;

        int k0 = (lane >> 4) * 8;
        int offj[8];
#pragma unroll
        for (int j = 0; j < 8; j++) {
            int k = k0 + j;
            int c = k / 9, r = (k % 9) / 3, q = k % 3;
            offj[j] = c * 1057 + r * 33 + q;
        }
        unsigned short* b1u16 = (unsigned short*)bits1;
        __syncthreads();

        for (int mt = wave; mt < 57; mt += 8) {   // M = 225*4 = 900 -> 57 tiles, 8 waves
            int mg = mt * 16 + (lane & 15);
            int me = mg < 900 ? mg : 899;
            int p = me >> 2, win = me & 3;
            int py = p / 15, px = p - py * 15;
            int base = (py * 2 + (win >> 1)) * 33 + px * 2 + (win & 1);
            v8h a;
#pragma unroll
            for (int j = 0; j < 8; j++)
                a[j] = (k0 + j < 27) ? xh[base + offj[j]] : (_Float16)0.f;
            HU ua; ua.h = a;                      // |A| for the error-bound MFMA
            ua.u.x &= 0x7FFF7FFFu; ua.u.y &= 0x7FFF7FFFu;
            ua.u.z &= 0x7FFF7FFFu; ua.u.w &= 0x7FFF7FFFu;
            int myp = mt * 4 + (lane >> 4);
#pragma unroll
            for (int nt = 0; nt < 8; nt++) {
                HU bs; bs.u = bfrag[nt * 64 + lane];
                HU ba; ba.u = bfraga[nt * 64 + lane];
                v4f s  = __builtin_amdgcn_mfma_f32_16x16x32_f16(a,    bs.h, (v4f){0.f,0.f,0.f,0.f}, 0, 0, 0);
                v4f sa = __builtin_amdgcn_mfma_f32_16x16x32_f16(ua.h, ba.h, (v4f){0.f,0.f,0.f,0.f}, 0, 0, 0);
                // rigorous f16-rounding bounds; sign logic as wave-mask ballots
                float bd0 = fmaf(sa[0], 1.1e-3f, 1e-5f);
                float bd1 = fmaf(sa[1], 1.1e-3f, 1e-5f);
                float bd2 = fmaf(sa[2], 1.1e-3f, 1e-5f);
                float bd3 = fmaf(sa[3], 1.1e-3f, 1e-5f);
                unsigned long long mkpos =
                    __ballot(s[0] >= bd0) | __ballot(s[1] >= bd1) |
                    __ballot(s[2] >= bd2) | __ballot(s[3] >= bd3);
                unsigned long long mkunc =
                    (__ballot(fabsf(s[0]) < bd0) | __ballot(fabsf(s[1]) < bd1) |
                     __ballot(fabsf(s[2]) < bd2) | __ballot(fabsf(s[3]) < bd3)) & ~mkpos;
                if ((lane & 15) == 0 && myp < 225)
                    b1u16[myp * 8 + nt] = (unsigned short)(mkpos >> (lane & 48));
                if (__builtin_expect(mkunc != 0ull, 0)) {
                    if (((mkunc >> lane) & 1ull) && myp < 225) {
                        unsigned int qi = atomicAdd(&qcnt, 1u);
                        if (qi < 256) queue[qi] = (unsigned)myp | ((unsigned)(nt * 16 + (lane & 15)) << 8);
                    }
                }
            }
        }
        __syncthreads();
        // ---- drain queue: exact f64 signs from GLOBAL f32 x (rare; all 4 windows) ----
        unsigned int nq = qcnt < 256u ? qcnt : 256u;
        for (unsigned int i = tid; i < nq; i += 512) {
            unsigned int e = queue[i];
            int p = e & 255; int oc = (e >> 8) & 255;
            int py = p / 15, px = p - py * 15;
            bool pos = false;
#pragma unroll
            for (int win = 0; win < 4; win++) {
                int base = (py * 2 + (win >> 1)) * 32 + px * 2 + (win & 1);
                double sd = 0.0;
#pragma unroll
                for (int k = 0; k < 27; k++) {
                    int c = k / 9, r = (k % 9) / 3, q = k % 3;
                    sd += (double)xb[base + c * 1024 + r * 32 + q] * (double)w0[oc * 27 + k];
                }
                pos |= (sd >= 0.0);
            }
            if (pos) atomicOr(&bits1[p * 2 + (oc >> 6)], 1ull << (oc & 63));
        }
    }
    __syncthreads();

    int wave2 = tid >> 6, half = wave2 & 1, pair = wave2 >> 1;   // pair 0..3
    int oc = half * 64 + lane;

    // ================= phase 1: binconv1 (15->13) + maxpool2 (->6) =================
    {
        unsigned long long wr[18];
#pragma unroll
        for (int j = 0; j < 18; j++) wr[j] = wb1[oc * 18 + j];
        const ulonglong2* b1v = (const ulonglong2*)bits1;
        for (int p = pair; p < 36; p += 4) {
            int py = p / 6, px = p % 6;
            int P0 = 0, P1 = 0, P2 = 0, P3 = 0;
#pragma unroll
            for (int yy = 0; yy < 4; yy++) {
                int rb = (2 * py + yy) * 15 + 2 * px;
                ulonglong2 q0 = b1v[rb];
                ulonglong2 q1 = b1v[rb + 1];
                ulonglong2 q2 = b1v[rb + 2];
                ulonglong2 q3 = b1v[rb + 3];
#pragma unroll
                for (int dy = 0; dy < 2; dy++) {
                    int ky = yy - dy;
                    if (ky < 0 || ky > 2) continue;
#pragma unroll
                    for (int kx = 0; kx < 3; kx++) {
                        ulonglong2 qa = kx == 0 ? q0 : (kx == 1 ? q1 : q2);
                        ulonglong2 qb = kx == 0 ? q1 : (kx == 1 ? q2 : q3);
                        int d0 = __popcll(qa.x ^ wr[(ky * 3 + kx) * 2]) +
                                 __popcll(qa.y ^ wr[(ky * 3 + kx) * 2 + 1]);
                        int d1 = __popcll(qb.x ^ wr[(ky * 3 + kx) * 2]) +
                                 __popcll(qb.y ^ wr[(ky * 3 + kx) * 2 + 1]);
                        if (dy == 0) { P0 += d0; P1 += d1; }
                        else         { P2 += d0; P3 += d1; }
                    }
                }
            }
            unsigned long long m = __ballot(P0 <= 576) | __ballot(P1 <= 576) |
                                   __ballot(P2 <= 576) | __ballot(P3 <= 576);
            if (lane == 0) bits2[p * 2 + half] = m;
        }
    }
    __syncthreads();

    // ================= phase 2: binconv2 (6->4) + maxpool(2,s1) (->3) =================
    {
        unsigned long long wr[18];
#pragma unroll
        for (int j = 0; j < 18; j++) wr[j] = wb2[oc * 18 + j];
        const ulonglong2* b2v = (const ulonglong2*)bits2;
        for (int p = pair; p < 9; p += 4) {
            int py = p / 3, px = p % 3;
            int P4[4];
#pragma unroll
            for (int dy = 0; dy < 2; dy++)
#pragma unroll
                for (int dx = 0; dx < 2; dx++) {
                    int P = 0;
#pragma unroll
                    for (int ky = 0; ky < 3; ky++)
#pragma unroll
                        for (int kx = 0; kx < 3; kx++) {
                            ulonglong2 q = b2v[(py + dy + ky) * 6 + (px + dx + kx)];
                            P += __popcll(q.x ^ wr[(ky * 3 + kx) * 2]);
                            P += __popcll(q.y ^ wr[(ky * 3 + kx) * 2 + 1]);
                        }
                    P4[dy * 2 + dx] = P;
                }
            unsigned long long m = __ballot(P4[0] <= 576) | __ballot(P4[1] <= 576) |
                                   __ballot(P4[2] <= 576) | __ballot(P4[3] <= 576);
            if (lane == 0) bits3[p * 2 + half] = m;
        }
    }
    __syncthreads();

    // ================= phase 3: binconv3 + binconv4 + relu + w5 + softmax =================
    if (tid < 128) {
        int P = 0;
#pragma unroll
        for (int k = 0; k < 9; k++) {
            P += __popcll(bits3[k * 2] ^ wb3[tid * 18 + k * 2]);
            P += __popcll(bits3[k * 2 + 1] ^ wb3[tid * 18 + k * 2 + 1]);
        }
        unsigned long long m = __ballot(P <= 576);
        if ((tid & 63) == 0) bits4[tid >> 6] = m;
    }
    __syncthreads();
    if (tid < 128) {
        unsigned long long i0 = bits4[0], i1 = bits4[1];
        int v = 128 - 2 * (int)(__popcll(i0 ^ wb4[tid * 2]) + __popcll(i1 ^ wb4[tid * 2 + 1]));
        r_s[tid] = v > 0 ? (float)v : 0.f;   // relu
    }
    __syncthreads();
    if (tid < NUM_CLS) {
        float l = 0.f;
#pragma unroll 8
        for (int k = 0; k < 128; k++) l = fmaf(w5[tid * 128 + k], r_s[k], l);
        l_s[tid] = l;
    }
    __syncthreads();
    if (tid < NUM_CLS) {
        float mx = -1e30f;
        for (int k = 0; k < NUM_CLS; k++) mx = fmaxf(mx, l_s[k]);
        e_s[tid] = expf(l_s[tid] - mx);
    }
    __syncthreads();
    if (tid < NUM_CLS) {
        float sum = 0.f;
        for (int k = 0; k < NUM_CLS; k++) sum += e_s[k];
        out[(size_t)b * NUM_CLS + tid] = e_s[tid] / sum;
    }
}

extern "C" void kernel_launch(void* const* d_in, const int* in_sizes, int n_in,
                              void* d_out, int out_size, void* d_ws, size_t ws_size,
                              hipStream_t stream) {
    const float* x  = (const float*)d_in[0];
    const float* w0 = (const float*)d_in[1];
    const float* w1 = (const float*)d_in[2];
    const float* w2 = (const float*)d_in[3];
    const float* w3 = (const float*)d_in[4];
    const float* w4 = (const float*)d_in[5];
    const float* w5 = (const float*)d_in[6];
    float* out = (float*)d_out;

    int B = in_sizes[0] / 3072;   // 1024

    size_t off = 0;
    auto carve = [&](size_t bytes) {
        void* p = (char*)d_ws + off;
        off += (bytes + 255) & ~(size_t)255;
        return p;
    };
    unsigned long long* wb1 = (unsigned long long*)carve(1152 * 2 * 8);
    unsigned long long* wb2 = (unsigned long long*)carve(1152 * 2 * 8);
    unsigned long long* wb3 = (unsigned long long*)carve(1152 * 2 * 8);
    unsigned long long* wb4 = (unsigned long long*)carve(128 * 2 * 8);
    _Float16* bsig = (_Float16*)carve(8 * 64 * 8 * 2);   // MFMA B-frags (signed)
    _Float16* babs = (_Float16*)carve(8 * 64 * 8 * 2);   // MFMA B-frags (abs)
    (void)ws_size; (void)n_in; (void)out_size;

    prep_all<<<418, 256, 0, stream>>>(w0, w1, w2, w3, w4, wb1, wb2, wb3, wb4, bsig, babs);
    fused_net<<<B, 512, 0, stream>>>(x, w0, bsig, babs, wb1, wb2, wb3, wb4, w5, out);
}

// Round 21
// 174.496 us; speedup vs baseline: 1.6972x; 1.6972x over previous
//
#include <hip/hip_runtime.h>
#include <cmath>

#define NUM_CLS 58

typedef _Float16 v8h __attribute__((ext_vector_type(8)));
typedef float v4f __attribute__((ext_vector_type(4)));
union HU { v8h h; uint4 u; };

// ---------------- prep: 256-thread blocks, coalesced staging ----------------
__global__ __launch_bounds__(256) void prep_all(
    const float* __restrict__ w0, const float* __restrict__ w1,
    const float* __restrict__ w2, const float* __restrict__ w3,
    const float* __restrict__ w4,
    unsigned long long* __restrict__ wb1, unsigned long long* __restrict__ wb2,
    unsigned long long* __restrict__ wb3, unsigned long long* __restrict__ wb4,
    _Float16* __restrict__ bsig, _Float16* __restrict__ babs) {
    int id = blockIdx.x, tid = threadIdx.x;
    int lane = tid & 63, wv = tid >> 6;
    if (id < 384) {
        int layer = id >> 7, oc = id & 127;
        const float* w = layer == 0 ? w1 : (layer == 1 ? w2 : w3);
        unsigned long long* o = layer == 0 ? wb1 : (layer == 1 ? wb2 : wb3);
        __shared__ float s[1152];
        const float* base = w + (size_t)oc * 1152;
        for (int i = tid; i < 1152; i += 256) s[i] = base[i];   // coalesced
        __syncthreads();
        for (int k = wv; k < 9; k += 4) {
            unsigned long long b0 = __ballot(s[lane * 9 + k] >= 0.f);
            unsigned long long b1 = __ballot(s[(lane + 64) * 9 + k] >= 0.f);
            if (lane == 0) { o[(oc * 9 + k) * 2] = b0; o[(oc * 9 + k) * 2 + 1] = b1; }
        }
    } else if (id < 416) {
        int oc = (id - 384) * 4 + wv;
        unsigned long long b0 = __ballot(w4[oc * 128 + lane] >= 0.f);
        unsigned long long b1 = __ballot(w4[oc * 128 + lane + 64] >= 0.f);
        if (lane == 0) { wb4[oc * 2] = b0; wb4[oc * 2 + 1] = b1; }
    } else {
        int nt = (id - 416) * 4 + wv;
        int n = nt * 16 + (lane & 15);
        int k0 = (lane >> 4) * 8;
#pragma unroll
        for (int j = 0; j < 8; j++) {
            int k = k0 + j;
            float v = (k < 27) ? w0[n * 27 + k] : 0.f;
            bsig[(nt * 64 + lane) * 8 + j] = (_Float16)v;
            babs[(nt * 64 + lane) * 8 + j] = (_Float16)fabsf(v);
        }
    }
}

// ---- kernel A: conv0 via f16 MFMA, one block = (image, oc-half) ----
// 2048 blocks x 256 thr => 8 blocks/CU (LDS 17.6K allows 9) = 32 waves/CU for
// the dominant phase. 256-thread blocks are mandatory: allocator gives
// VGPR = 256/waves-per-block (r20: 512-thr block -> 32 VGPR -> 268 MB spill).
__global__ __launch_bounds__(256, 4) void conv0_half(
    const float* __restrict__ x, const float* __restrict__ w0,
    const _Float16* __restrict__ bsigG, const _Float16* __restrict__ babsG,
    unsigned long long* __restrict__ bits1G) {   // [B][2][225]
    __shared__ _Float16 xh[3172];              // image f16; row stride 33, chan 1057
    __shared__ uint4 bfrag[256];               // this half's B sign-frags (4 KB)
    __shared__ uint4 bfraga[256];              // this half's |B| frags (4 KB)
    __shared__ alignas(16) unsigned long long bits1h[225];
    __shared__ unsigned int qcnt;
    __shared__ unsigned int queue[256];

    int bid = blockIdx.x;
    int b = bid >> 1, half = bid & 1;
    int tid = threadIdx.x;
    int lane = tid & 63, wave = tid >> 6;
    const float* xb = x + (size_t)b * 3072;

    for (int i = tid; i < 3072; i += 256) {
        int c = i >> 10, rem = i & 1023;
        xh[c * 1057 + (rem >> 5) * 33 + (rem & 31)] = (_Float16)xb[i];
    }
    const uint4* bs4 = (const uint4*)bsigG + half * 256;
    const uint4* ba4 = (const uint4*)babsG + half * 256;
    if (tid < 256) { bfrag[tid] = bs4[tid]; bfraga[tid] = ba4[tid]; }
    if (tid == 0) qcnt = 0;

    int col = lane & 15;
    int k0 = (lane >> 4) * 8;
    int offj[8];
#pragma unroll
    for (int j = 0; j < 8; j++) {
        int k = k0 + j;
        int c = k / 9, r = (k % 9) / 3, q = k % 3;
        offj[j] = c * 1057 + r * 33 + q;
    }
    unsigned short* b1u16 = (unsigned short*)bits1h;
    __syncthreads();

    for (int mt = wave; mt < 57; mt += 4) {   // M = 225*4 = 900 -> 57 tiles
        int mg = mt * 16 + col;
        int me = mg < 900 ? mg : 899;
        int p = me >> 2, win = me & 3;
        int py = p / 15, px = p - py * 15;
        int base = (py * 2 + (win >> 1)) * 33 + px * 2 + (win & 1);
        v8h a;
#pragma unroll
        for (int j = 0; j < 8; j++)
            a[j] = (k0 + j < 27) ? xh[base + offj[j]] : (_Float16)0.f;
        HU ua; ua.h = a;                      // |A| for the error-bound MFMA
        ua.u.x &= 0x7FFF7FFFu; ua.u.y &= 0x7FFF7FFFu;
        ua.u.z &= 0x7FFF7FFFu; ua.u.w &= 0x7FFF7FFFu;
        int myp = mt * 4 + (lane >> 4);
#pragma unroll
        for (int ntl = 0; ntl < 4; ntl++) {   // 4 nt tiles = this oc-half
            HU bs; bs.u = bfrag[ntl * 64 + lane];
            HU ba; ba.u = bfraga[ntl * 64 + lane];
            v4f s  = __builtin_amdgcn_mfma_f32_16x16x32_f16(a,    bs.h, (v4f){0.f,0.f,0.f,0.f}, 0, 0, 0);
            v4f sa = __builtin_amdgcn_mfma_f32_16x16x32_f16(ua.h, ba.h, (v4f){0.f,0.f,0.f,0.f}, 0, 0, 0);
            float bd0 = fmaf(sa[0], 1.1e-3f, 1e-5f);   // rigorous f16-rounding bound
            float bd1 = fmaf(sa[1], 1.1e-3f, 1e-5f);
            float bd2 = fmaf(sa[2], 1.1e-3f, 1e-5f);
            float bd3 = fmaf(sa[3], 1.1e-3f, 1e-5f);
            unsigned long long mkpos =
                __ballot(s[0] >= bd0) | __ballot(s[1] >= bd1) |
                __ballot(s[2] >= bd2) | __ballot(s[3] >= bd3);
            unsigned long long mkunc =
                (__ballot(fabsf(s[0]) < bd0) | __ballot(fabsf(s[1]) < bd1) |
                 __ballot(fabsf(s[2]) < bd2) | __ballot(fabsf(s[3]) < bd3)) & ~mkpos;
            if ((lane & 15) == 0 && myp < 225)
                b1u16[myp * 4 + ntl] = (unsigned short)(mkpos >> (lane & 48));
            if (__builtin_expect(mkunc != 0ull, 0)) {
                if (((mkunc >> lane) & 1ull) && myp < 225) {
                    unsigned int qi = atomicAdd(&qcnt, 1u);
                    if (qi < 256) queue[qi] = (unsigned)myp | ((unsigned)(ntl * 16 + col) << 8);
                }
            }
        }
    }
    __syncthreads();
    // ---- drain queue: exact f64 signs from GLOBAL f32 x (rare; all 4 windows) ----
    unsigned int nq = qcnt < 256u ? qcnt : 256u;
    for (unsigned int i = tid; i < nq; i += 256) {
        unsigned int e = queue[i];
        int p = e & 255; int ocl = (e >> 8) & 255;   // local oc 0..63
        int oc = half * 64 + ocl;
        int py = p / 15, px = p - py * 15;
        bool pos = false;
#pragma unroll
        for (int win = 0; win < 4; win++) {
            int base = (py * 2 + (win >> 1)) * 32 + px * 2 + (win & 1);
            double sd = 0.0;
#pragma unroll
            for (int k = 0; k < 27; k++) {
                int c = k / 9, r = (k % 9) / 3, q = k % 3;
                sd += (double)xb[base + c * 1024 + r * 32 + q] * (double)w0[oc * 27 + k];
            }
            pos |= (sd >= 0.0);
        }
        if (pos) atomicOr(&bits1h[p], 1ull << ocl);
    }
    __syncthreads();
    unsigned long long* dst = bits1G + (size_t)(b * 2 + half) * 225;
    for (int i = tid; i < 225; i += 256) dst[i] = bits1h[i];   // coalesced
}

// ---- kernel B: phases 1-3 (r17-verbatim), bits1 restaged from global ----
__global__ __launch_bounds__(256, 4) void tail_net(
    const unsigned long long* __restrict__ bits1G,
    const unsigned long long* __restrict__ wb1, const unsigned long long* __restrict__ wb2,
    const unsigned long long* __restrict__ wb3, const unsigned long long* __restrict__ wb4,
    const float* __restrict__ w5, float* __restrict__ out) {
    __shared__ alignas(16) unsigned long long bits1[450];  // [225][2]
    __shared__ alignas(16) unsigned long long bits2[72];
    __shared__ unsigned long long bits3[18];
    __shared__ unsigned long long bits4[2];
    __shared__ float r_s[128];
    __shared__ float l_s[NUM_CLS];
    __shared__ float e_s[NUM_CLS];

    int b = blockIdx.x;
    int tid = threadIdx.x;
    int lane = tid & 63;
    {
        const unsigned long long* src = bits1G + (size_t)b * 450;   // [2][225]
        for (int i = tid; i < 450; i += 256) {
            int half = i >= 225, p = i - half * 225;
            bits1[p * 2 + half] = src[i];   // global coalesced, LDS stride-2
        }
    }
    __syncthreads();

    int wave2 = tid >> 6, half = wave2 & 1, pair = wave2 >> 1;
    int oc = half * 64 + lane;

    // ================= phase 1: binconv1 (15->13) + maxpool2 (->6) =================
    {
        unsigned long long wr[18];
#pragma unroll
        for (int j = 0; j < 18; j++) wr[j] = wb1[oc * 18 + j];
        const ulonglong2* b1v = (const ulonglong2*)bits1;
        for (int p = pair; p < 36; p += 2) {
            int py = p / 6, px = p % 6;
            int P0 = 0, P1 = 0, P2 = 0, P3 = 0;
#pragma unroll
            for (int yy = 0; yy < 4; yy++) {
                int rb = (2 * py + yy) * 15 + 2 * px;
                ulonglong2 q0 = b1v[rb];
                ulonglong2 q1 = b1v[rb + 1];
                ulonglong2 q2 = b1v[rb + 2];
                ulonglong2 q3 = b1v[rb + 3];
#pragma unroll
                for (int dy = 0; dy < 2; dy++) {
                    int ky = yy - dy;
                    if (ky < 0 || ky > 2) continue;
#pragma unroll
                    for (int kx = 0; kx < 3; kx++) {
                        ulonglong2 qa = kx == 0 ? q0 : (kx == 1 ? q1 : q2);
                        ulonglong2 qb = kx == 0 ? q1 : (kx == 1 ? q2 : q3);
                        int d0 = __popcll(qa.x ^ wr[(ky * 3 + kx) * 2]) +
                                 __popcll(qa.y ^ wr[(ky * 3 + kx) * 2 + 1]);
                        int d1 = __popcll(qb.x ^ wr[(ky * 3 + kx) * 2]) +
                                 __popcll(qb.y ^ wr[(ky * 3 + kx) * 2 + 1]);
                        if (dy == 0) { P0 += d0; P1 += d1; }
                        else         { P2 += d0; P3 += d1; }
                    }
                }
            }
            unsigned long long m = __ballot(P0 <= 576) | __ballot(P1 <= 576) |
                                   __ballot(P2 <= 576) | __ballot(P3 <= 576);
            if (lane == 0) bits2[p * 2 + half] = m;
        }
    }
    __syncthreads();

    // ================= phase 2: binconv2 (6->4) + maxpool(2,s1) (->3) =================
    {
        unsigned long long wr[18];
#pragma unroll
        for (int j = 0; j < 18; j++) wr[j] = wb2[oc * 18 + j];
        const ulonglong2* b2v = (const ulonglong2*)bits2;
        for (int p = pair; p < 9; p += 2) {
            int py = p / 3, px = p % 3;
            int P4[4];
#pragma unroll
            for (int dy = 0; dy < 2; dy++)
#pragma unroll
                for (int dx = 0; dx < 2; dx++) {
                    int P = 0;
#pragma unroll
                    for (int ky = 0; ky < 3; ky++)
#pragma unroll
                        for (int kx = 0; kx < 3; kx++) {
                            ulonglong2 q = b2v[(py + dy + ky) * 6 + (px + dx + kx)];
                            P += __popcll(q.x ^ wr[(ky * 3 + kx) * 2]);
                            P += __popcll(q.y ^ wr[(ky * 3 + kx) * 2 + 1]);
                        }
                    P4[dy * 2 + dx] = P;
                }
            unsigned long long m = __ballot(P4[0] <= 576) | __ballot(P4[1] <= 576) |
                                   __ballot(P4[2] <= 576) | __ballot(P4[3] <= 576);
            if (lane == 0) bits3[p * 2 + half] = m;
        }
    }
    __syncthreads();

    // ================= phase 3: binconv3 + binconv4 + relu + w5 + softmax =================
    if (tid < 128) {
        int P = 0;
#pragma unroll
        for (int k = 0; k < 9; k++) {
            P += __popcll(bits3[k * 2] ^ wb3[tid * 18 + k * 2]);
            P += __popcll(bits3[k * 2 + 1] ^ wb3[tid * 18 + k * 2 + 1]);
        }
        unsigned long long m = __ballot(P <= 576);
        if ((tid & 63) == 0) bits4[tid >> 6] = m;
    }
    __syncthreads();
    if (tid < 128) {
        unsigned long long i0 = bits4[0], i1 = bits4[1];
        int v = 128 - 2 * (int)(__popcll(i0 ^ wb4[tid * 2]) + __popcll(i1 ^ wb4[tid * 2 + 1]));
        r_s[tid] = v > 0 ? (float)v : 0.f;   // relu
    }
    __syncthreads();
    if (tid < NUM_CLS) {
        float l = 0.f;
#pragma unroll 8
        for (int k = 0; k < 128; k++) l = fmaf(w5[tid * 128 + k], r_s[k], l);
        l_s[tid] = l;
    }
    __syncthreads();
    if (tid < NUM_CLS) {
        float mx = -1e30f;
        for (int k = 0; k < NUM_CLS; k++) mx = fmaxf(mx, l_s[k]);
        e_s[tid] = expf(l_s[tid] - mx);
    }
    __syncthreads();
    if (tid < NUM_CLS) {
        float sum = 0.f;
        for (int k = 0; k < NUM_CLS; k++) sum += e_s[k];
        out[(size_t)b * NUM_CLS + tid] = e_s[tid] / sum;
    }
}

extern "C" void kernel_launch(void* const* d_in, const int* in_sizes, int n_in,
                              void* d_out, int out_size, void* d_ws, size_t ws_size,
                              hipStream_t stream) {
    const float* x  = (const float*)d_in[0];
    const float* w0 = (const float*)d_in[1];
    const float* w1 = (const float*)d_in[2];
    const float* w2 = (const float*)d_in[3];
    const float* w3 = (const float*)d_in[4];
    const float* w4 = (const float*)d_in[5];
    const float* w5 = (const float*)d_in[6];
    float* out = (float*)d_out;

    int B = in_sizes[0] / 3072;   // 1024

    size_t off = 0;
    auto carve = [&](size_t bytes) {
        void* p = (char*)d_ws + off;
        off += (bytes + 255) & ~(size_t)255;
        return p;
    };
    unsigned long long* wb1 = (unsigned long long*)carve(1152 * 2 * 8);
    unsigned long long* wb2 = (unsigned long long*)carve(1152 * 2 * 8);
    unsigned long long* wb3 = (unsigned long long*)carve(1152 * 2 * 8);
    unsigned long long* wb4 = (unsigned long long*)carve(128 * 2 * 8);
    _Float16* bsig = (_Float16*)carve(8 * 64 * 8 * 2);          // MFMA B-frags (signed)
    _Float16* babs = (_Float16*)carve(8 * 64 * 8 * 2);          // MFMA B-frags (abs)
    unsigned long long* bits1G = (unsigned long long*)carve((size_t)B * 450 * 8);
    (void)ws_size; (void)n_in; (void)out_size;

    prep_all<<<418, 256, 0, stream>>>(w0, w1, w2, w3, w4, wb1, wb2, wb3, wb4, bsig, babs);
    conv0_half<<<B * 2, 256, 0, stream>>>(x, w0, bsig, babs, bits1G);
    tail_net<<<B, 256, 0, stream>>>(bits1G, wb1, wb2, wb3, wb4, w5, out);
}